// Round 6
// baseline (492.562 us; speedup 1.0000x reference)
//
#include <hip/hip_runtime.h>
#include <hip/hip_bf16.h>

// Problem constants (B=4, L=2048, D=512, M=1200, H=6)
// KEY INSIGHT: keyval is broadcast over L -> K rows identical -> softmax == 1/L exactly,
// mha == V[b] (per-batch constant), and leaky(slope=1) is identity so W2a@W2b folds.
// R14 = R13 work-kernels + sm-fill moved OUT of the kernels into a single
// hipMemsetD32Async (1/2048f == 0x3A000000 -> D32-memsettable). Rationale: R12/R13
// work-traffic cuts moved dur_us ~0 -> kernels are fill-bound, and mixed read/write
// streams run well below the pure-write ceiling that fillBufferAligned demonstrates
// (6.25 TB/s). One pure-write memset moves the same 402.6 MB at ceiling (~64us).
// Kernels shrink to work-only grids: k1 2336, k3 384, k4 8448, k5 256, k6 8192.

typedef __bf16 bf16x8 __attribute__((ext_vector_type(8)));
typedef float f32x4 __attribute__((ext_vector_type(4)));

constexpr size_t OUT3_N = 4ull * 2048 * 512;            // 4,194,304 floats
constexpr size_t SM_N   = 4ull * 6 * 2048 * 2048;       // 100,663,296 floats
// 1.0f/2048.0f bit pattern
constexpr int SMV_BITS = 0x3A000000;

// ---------------- bf16 MFMA GEMM tile: C[64x64 at bm,bn] (+)= A[M,K] @ BT[N,K]^T over [k0beg,k0end)
// BK=64, 4 waves 2x2, global_load_lds width16, XOR-swizzled LDS (16B chunks: c8' = c8 ^ (r&7))
// MODE: 1 = atomicAdd fp32 (split-K), 2 = store bf16
template<int MODE, typename OutT>
__device__ void gemm_tile(const __bf16* __restrict__ A, const __bf16* __restrict__ BT,
                          OutT* __restrict__ C, int Ndim, int Kdim,
                          int bm, int bn, int k0beg, int k0end){
    __shared__ __bf16 As[64 * 64];
    __shared__ __bf16 Bs[64 * 64];
    const int tid = threadIdx.x, wave = tid >> 6, lane = tid & 63;
    const int r_st = wave * 8 + (lane >> 3);
    const int c8g  = (lane & 7) ^ (r_st & 7);
    const __bf16* Ag = A  + (size_t)(bm + r_st) * Kdim + c8g * 8;
    const __bf16* Bg = BT + (size_t)(bn + r_st) * Kdim + c8g * 8;
    const size_t rowskip = (size_t)32 * Kdim;
    const int wm = (wave >> 1) * 32, wn = (wave & 1) * 32;
    const int lm = lane & 15, lq = lane >> 4;
    f32x4 acc[2][2] = {};
    for (int k0 = k0beg; k0 < k0end; k0 += 64){
        __builtin_amdgcn_global_load_lds(
            (const __attribute__((address_space(1))) void*)(Ag + k0),
            (__attribute__((address_space(3))) void*)&As[wave * 512], 16, 0, 0);
        __builtin_amdgcn_global_load_lds(
            (const __attribute__((address_space(1))) void*)(Ag + k0 + rowskip),
            (__attribute__((address_space(3))) void*)&As[2048 + wave * 512], 16, 0, 0);
        __builtin_amdgcn_global_load_lds(
            (const __attribute__((address_space(1))) void*)(Bg + k0),
            (__attribute__((address_space(3))) void*)&Bs[wave * 512], 16, 0, 0);
        __builtin_amdgcn_global_load_lds(
            (const __attribute__((address_space(1))) void*)(Bg + k0 + rowskip),
            (__attribute__((address_space(3))) void*)&Bs[2048 + wave * 512], 16, 0, 0);
        __syncthreads();
        #pragma unroll
        for (int kb = 0; kb < 64; kb += 32){
            const int sw = (((kb >> 3) + lq) ^ (lm & 7)) << 3;
            bf16x8 a0 = *(const bf16x8*)&As[(wm + lm) * 64 + sw];
            bf16x8 a1 = *(const bf16x8*)&As[(wm + 16 + lm) * 64 + sw];
            bf16x8 b0 = *(const bf16x8*)&Bs[(wn + lm) * 64 + sw];
            bf16x8 b1 = *(const bf16x8*)&Bs[(wn + 16 + lm) * 64 + sw];
            acc[0][0] = __builtin_amdgcn_mfma_f32_16x16x32_bf16(a0, b0, acc[0][0], 0, 0, 0);
            acc[0][1] = __builtin_amdgcn_mfma_f32_16x16x32_bf16(a0, b1, acc[0][1], 0, 0, 0);
            acc[1][0] = __builtin_amdgcn_mfma_f32_16x16x32_bf16(a1, b0, acc[1][0], 0, 0, 0);
            acc[1][1] = __builtin_amdgcn_mfma_f32_16x16x32_bf16(a1, b1, acc[1][1], 0, 0, 0);
        }
        __syncthreads();
    }
    #pragma unroll
    for (int mi = 0; mi < 2; ++mi)
      #pragma unroll
      for (int ni = 0; ni < 2; ++ni)
        #pragma unroll
        for (int r = 0; r < 4; ++r){
            int row = bm + wm + mi * 16 + lq * 4 + r;   // C/D: row=(lane>>4)*4+reg
            int col = bn + wn + ni * 16 + lm;           //      col=lane&15
            if (MODE == 1) atomicAdd((float*)&C[(size_t)row * Ndim + col], acc[mi][ni][r]);
            else           C[(size_t)row * Ndim + col] = (OutT)acc[mi][ni][r];
        }
}

// ---------------- k1: prep + kv split-K (work-only) ----------------
__global__ __launch_bounds__(256) void k1_prep_kv(const float* __restrict__ W2a,
        const float* __restrict__ b2a, __bf16* __restrict__ A1,
        const float* __restrict__ W2b, __bf16* __restrict__ W2bT,
        const float* __restrict__ keyval, const float* __restrict__ Wkv,
        const float* __restrict__ bkv, float* __restrict__ V){
    __shared__ float sh[32 * 33];
    const int bid = blockIdx.x, tid = threadIdx.x;
    if (bid < 1152){
        int r = bid >> 1;
        int c = (bid & 1) * 1024 + tid * 4;
        float4 v;
        if (r < 512)       v = *(const float4*)(W2a + (size_t)r * 2048 + c);
        else if (r == 512) v = *(const float4*)(b2a + c);
        else               v = make_float4(0.f, 0.f, 0.f, 0.f);
        union { __bf16 h[4]; ushort4 u; } pk;
        pk.h[0] = (__bf16)v.x; pk.h[1] = (__bf16)v.y;
        pk.h[2] = (__bf16)v.z; pk.h[3] = (__bf16)v.w;
        *(ushort4*)(A1 + (size_t)r * 2048 + c) = pk.u;
    } else if (bid < 2176){
        int t = bid - 1152;                    // 1024 tiles over W2b [2048][512]
        int c0 = (t & 15) * 32, r0 = (t >> 4) * 32;
        int tx = tid & 31, ty = tid >> 5;
        for (int i = ty; i < 32; i += 8)
            sh[i * 33 + tx] = W2b[(size_t)(r0 + i) * 512 + c0 + tx];
        __syncthreads();
        for (int i = ty; i < 32; i += 8)
            W2bT[(size_t)(c0 + i) * 2048 + r0 + tx] = (__bf16)sh[tx * 33 + i];
    } else {
        int i = bid - 2176;                    // 160: b(4) x mc(5) x kc(8)
        int b = i & 3, mc = (i >> 2) % 5, kc = i / 20;
        int m = mc * 256 + tid;
        if (m < 1200){
            float acc = (kc == 0) ? bkv[1200 + m] : 0.f;
            const float* kvb = keyval + (size_t)b * 512;
            int d0 = kc * 64;
            #pragma unroll 8
            for (int d = d0; d < d0 + 64; ++d)
                acc += kvb[d] * Wkv[(size_t)d * 2400 + 1200 + m];
            atomicAdd(&V[b * 1200 + m], acc);
        }
    }
}

// ---------------- k3: fold GEMM split-K + oc GEMV (work-only) ----------------
__global__ __launch_bounds__(256) void k3_fold_oc(const __bf16* __restrict__ A1,
        const __bf16* __restrict__ W2bT, float* __restrict__ Wf,
        const float* __restrict__ V, const float* __restrict__ Wff,
        const float* __restrict__ bff, float* __restrict__ oc){
    const int bid = blockIdx.x, tid = threadIdx.x;
    if (bid < 288){                            // tile(9x8) x kc(4) over [576x512], K=2048
        int tile = bid % 72, kc = bid / 72;
        gemm_tile<1>(A1, W2bT, Wf, 512, 2048, (tile % 9) * 64, (tile / 9) * 64,
                     kc * 512, (kc + 1) * 512);
    } else {                                   // oc: b(4) x jc(2) x kc(12), K=1200
        int i = bid - 288;
        int b = i & 3, jc = (i >> 2) & 1, kc = i >> 3;
        int j = jc * 256 + tid;
        float acc = (kc == 0) ? bff[j] : 0.f;
        const float* vb = V + b * 1200;
        int m0 = kc * 100;
        #pragma unroll 5
        for (int m = m0; m < m0 + 100; ++m)
            acc += vb[m] * Wff[(size_t)m * 512 + j];
        atomicAdd(&oc[b * 512 + j], acc);
    }
}

// ---------------- k4: ln1 + tcast Wf->WfT (work-only) ----------------
__global__ __launch_bounds__(256) void k4_ln1_tcast(const float* __restrict__ q,
        const float* __restrict__ oc, const float* __restrict__ g1,
        const float* __restrict__ b1, __bf16* __restrict__ Xb,
        const float* __restrict__ Wf, __bf16* __restrict__ WfT){
    __shared__ float sh[32 * 33];
    const int bid = blockIdx.x, t = threadIdx.x;
    if (bid < 8192){
        const int b = bid >> 11;
        const size_t base = (size_t)bid * 512;
        float2 qv = *(const float2*)(q + base + 2 * t);
        float2 ov = *(const float2*)(oc + (size_t)b * 512 + 2 * t);
        float v0 = qv.x + ov.x, v1 = qv.y + ov.y;
        float s = v0 + v1, ss = v0 * v0 + v1 * v1;
        for (int off = 32; off; off >>= 1){ s += __shfl_down(s, off); ss += __shfl_down(ss, off); }
        int wv = t >> 6, ln = t & 63;
        if (ln == 0){ sh[wv] = s; sh[4 + wv] = ss; }
        __syncthreads();
        if (t == 0){
            float S  = sh[0] + sh[1] + sh[2] + sh[3];
            float SS = sh[4] + sh[5] + sh[6] + sh[7];
            float m = S * (1.0f / 512.0f);
            float var = SS * (1.0f / 512.0f) - m * m;
            sh[0] = m; sh[1] = rsqrtf(var + 1e-5f);
        }
        __syncthreads();
        float m = sh[0], r = sh[1];
        float2 gv = *(const float2*)(g1 + 2 * t);
        float2 bv = *(const float2*)(b1 + 2 * t);
        union { __bf16 h[2]; unsigned u; } pk;
        pk.h[0] = (__bf16)((v0 - m) * r * gv.x + bv.x);
        pk.h[1] = (__bf16)((v1 - m) * r * gv.y + bv.y);
        *(unsigned*)(Xb + base + 2 * t) = pk.u;
    } else {
        int tt = bid - 8192;                   // 256 tiles over Wf [512][512]
        int c0 = (tt & 15) * 32, r0 = (tt >> 4) * 32;
        int tx = t & 31, ty = t >> 5;
        for (int i = ty; i < 32; i += 8)
            sh[i * 33 + tx] = Wf[(size_t)(r0 + i) * 512 + c0 + tx];
        __syncthreads();
        for (int i = ty; i < 32; i += 8)
            WfT[(size_t)(c0 + i) * 512 + r0 + tx] = (__bf16)sh[tx * 33 + i];
    }
}

// ---------------- k5: main GEMM (out2' = X @ Wfold + X, bf16 out), 128x128 tiles ------
// 256 blocks (64 m-tiles x 4 n-tiles), 32KB LDS, acc[4][4] per wave.
// Epilogue adds the X residual so k6 never reads X.
__global__ __launch_bounds__(256) void k5_gemm(const __bf16* __restrict__ X,
        const __bf16* __restrict__ WfT, __bf16* __restrict__ out2){
    const int bid = blockIdx.x;
    __shared__ __bf16 As[128 * 64];        // 16 KB
    __shared__ __bf16 Bs[128 * 64];        // 16 KB
    const int bm = (bid >> 2) * 128, bn = (bid & 3) * 128;
    const int tid = threadIdx.x, wave = tid >> 6, lane = tid & 63;
    const int r_st = wave * 8 + (lane >> 3);
    const int c8g  = (lane & 7) ^ (r_st & 7);
    const __bf16* Ag = X   + (size_t)(bm + r_st) * 512 + c8g * 8;
    const __bf16* Bg = WfT + (size_t)(bn + r_st) * 512 + c8g * 8;
    const size_t rowskip = (size_t)32 * 512;
    const int wm = (wave >> 1) * 64, wn = (wave & 1) * 64;
    const int lm = lane & 15, lq = lane >> 4;
    f32x4 acc[4][4] = {};
    for (int k0 = 0; k0 < 512; k0 += 64){
        #pragma unroll
        for (int j = 0; j < 4; ++j){
            __builtin_amdgcn_global_load_lds(
                (const __attribute__((address_space(1))) void*)(Ag + k0 + j * rowskip),
                (__attribute__((address_space(3))) void*)&As[j * 2048 + wave * 512],
                16, 0, 0);
            __builtin_amdgcn_global_load_lds(
                (const __attribute__((address_space(1))) void*)(Bg + k0 + j * rowskip),
                (__attribute__((address_space(3))) void*)&Bs[j * 2048 + wave * 512],
                16, 0, 0);
        }
        __syncthreads();
        #pragma unroll
        for (int kb = 0; kb < 64; kb += 32){
            const int sw = (((kb >> 3) + lq) ^ (lm & 7)) << 3;
            bf16x8 a[4], b[4];
            #pragma unroll
            for (int j = 0; j < 4; ++j){
                a[j] = *(const bf16x8*)&As[(wm + j * 16 + lm) * 64 + sw];
                b[j] = *(const bf16x8*)&Bs[(wn + j * 16 + lm) * 64 + sw];
            }
            #pragma unroll
            for (int mi = 0; mi < 4; ++mi)
                #pragma unroll
                for (int ni = 0; ni < 4; ++ni)
                    acc[mi][ni] = __builtin_amdgcn_mfma_f32_16x16x32_bf16(
                        a[mi], b[ni], acc[mi][ni], 0, 0, 0);
        }
        __syncthreads();
    }
    #pragma unroll
    for (int mi = 0; mi < 4; ++mi)
      #pragma unroll
      for (int ni = 0; ni < 4; ++ni)
        #pragma unroll
        for (int r = 0; r < 4; ++r){
            int row = bm + wm + mi * 16 + lq * 4 + r;
            int col = bn + wn + ni * 16 + lm;
            float xv = (float)X[(size_t)row * 512 + col];
            out2[(size_t)row * 512 + col] = (__bf16)(acc[mi][ni][r] + xv);
        }
}

// ---------------- k6: ln2 (out2' already includes X) ----------------
__global__ __launch_bounds__(256) void k6_ln2(const __bf16* __restrict__ o2,
        const float* __restrict__ bfrow, const float* __restrict__ b2b,
        const float* __restrict__ g2, const float* __restrict__ b2,
        const float* __restrict__ keyval, float* __restrict__ out3){
    __shared__ float sh[8];
    const int bid = blockIdx.x, t = threadIdx.x;
    const int b = bid >> 11;
    const size_t base = (size_t)bid * 512;
    union { unsigned u; __bf16 h[2]; } yv;
    yv.u = *(const unsigned*)(o2 + base + 2 * t);
    float f0 = bfrow[2 * t] + b2b[2 * t], f1 = bfrow[2 * t + 1] + b2b[2 * t + 1];
    float v0 = (float)yv.h[0] + f0;
    float v1 = (float)yv.h[1] + f1;
    float s = v0 + v1, ss = v0 * v0 + v1 * v1;
    for (int off = 32; off; off >>= 1){ s += __shfl_down(s, off); ss += __shfl_down(ss, off); }
    int wv = t >> 6, ln = t & 63;
    if (ln == 0){ sh[wv] = s; sh[4 + wv] = ss; }
    __syncthreads();
    if (t == 0){
        float S  = sh[0] + sh[1] + sh[2] + sh[3];
        float SS = sh[4] + sh[5] + sh[6] + sh[7];
        float m = S * (1.0f / 512.0f);
        float var = SS * (1.0f / 512.0f) - m * m;
        sh[0] = m; sh[1] = rsqrtf(var + 1e-5f);
    }
    __syncthreads();
    float m = sh[0], r = sh[1];
    float2 gv = *(const float2*)(g2 + 2 * t);
    float2 bv = *(const float2*)(b2 + 2 * t);
    float2 kv = *(const float2*)(keyval + (size_t)b * 512 + 2 * t);
    float y0 = (v0 - m) * r * gv.x + bv.x + kv.x;
    float y1 = (v1 - m) * r * gv.y + bv.y + kv.y;
    *(float2*)(out3 + base + 2 * t) = make_float2(y0, y1);
}

// ---------------- launch ----------------
extern "C" void kernel_launch(void* const* d_in, const int* in_sizes, int n_in,
                              void* d_out, int out_size, void* d_ws, size_t ws_size,
                              hipStream_t stream){
    const float* query  = (const float*)d_in[0];
    const float* keyval = (const float*)d_in[1];
    // d_in[2] Wq, d_in[3] bq: provably unused (softmax is uniform regardless of Q)
    const float* Wkv = (const float*)d_in[4];
    const float* bkv = (const float*)d_in[5];
    const float* Wff = (const float*)d_in[6];
    const float* bff = (const float*)d_in[7];
    const float* g1  = (const float*)d_in[8];
    const float* b1  = (const float*)d_in[9];
    const float* W2a = (const float*)d_in[10];
    const float* b2a = (const float*)d_in[11];
    const float* W2b = (const float*)d_in[12];
    const float* b2b = (const float*)d_in[13];
    const float* g2  = (const float*)d_in[14];
    const float* b2  = (const float*)d_in[15];

    float* out3 = (float*)d_out;
    float* smf  = out3 + OUT3_N;

    // scratch (~24 MB): prefer d_ws; fall back to the sm region (filled last)
    char* base = (ws_size >= (64ull << 20)) ? (char*)d_ws : (char*)smf;
    float*  t_Wf   = (float*)base;                      // [576][512] fp32 (row 512 = b2a@W2b)
    float*  t_V    = t_Wf + 294912;                     // [4][1200]
    float*  t_oc   = t_V + 4800;                        // [4][512]
    __bf16* t_A1   = (__bf16*)(t_oc + 2048);            // [576][2048]
    __bf16* t_W2bT = t_A1 + 1179648;                    // [512][2048]
    __bf16* t_WfT  = t_W2bT + 1048576;                  // [512][512]
    __bf16* t_X    = t_WfT + 262144;                    // [8192][512]
    __bf16* t_out2 = t_X + 4194304;                     // [8192][512] bf16 (= out2 + X)

    // sm output: one pure-write D32 memset (1/2048f == 0x3A000000), ~402.6 MB at
    // pure-write ceiling (~64us) instead of distributed mixed-stream fills.
    (void)hipMemsetD32Async((hipDeviceptr_t)smf, SMV_BITS, SM_N, stream);
    // zero split-K accumulators (Wf, V, oc contiguous = 301,760 floats)
    (void)hipMemsetAsync(t_Wf, 0, 301760 * sizeof(float), stream);

    k1_prep_kv<<<2336, 256, 0, stream>>>(W2a, b2a, t_A1, W2b, t_W2bT,
                                         keyval, Wkv, bkv, t_V);
    k3_fold_oc<<<384, 256, 0, stream>>>(t_A1, t_W2bT, t_Wf, t_V, Wff, bff, t_oc);
    k4_ln1_tcast<<<8448, 256, 0, stream>>>(query, t_oc, g1, b1, t_X, t_Wf, t_WfT);
    k5_gemm<<<256, 256, 0, stream>>>(t_X, t_WfT, t_out2);
    // bfold row = row 512 of Wf (starts at 512*512)
    k6_ln2<<<8192, 256, 0, stream>>>(t_out2, t_Wf + 262144, b2b, g2, b2,
                                     keyval, out3);
}